// Round 1
// baseline (382.504 us; speedup 1.0000x reference)
//
#include <hip/hip_runtime.h>
#include <hip/hip_bf16.h>
#include <cstdint>

typedef _Float16 half8 __attribute__((ext_vector_type(8)));
typedef float f32x4 __attribute__((ext_vector_type(4)));

#define B_DIM 8
#define C_DIM 512
#define H_DIM 512
#define T_DIM 4096
#define KTOT 1024   // 2*C
#define MTOT 2048   // 4*H, interleaved m = 4*h + gate (z,f,o,i)

__device__ __forceinline__ void gload16(const void* g, void* l) {
  __builtin_amdgcn_global_load_lds(
      (const __attribute__((address_space(1))) unsigned int*)g,
      (__attribute__((address_space(3))) unsigned int*)l, 16, 0, 0);
}

__device__ __forceinline__ float sigmoidf_(float x) { return 1.0f / (1.0f + expf(-x)); }

// ---------------------------------------------------------------------------
// K0: pack weights fp32 [H][C][2] (4 gates) -> fp16 A16[m=4h+g][k=j*512+c]
// ---------------------------------------------------------------------------
__global__ __launch_bounds__(256) void pack_w(
    const float* __restrict__ wz, const float* __restrict__ wf,
    const float* __restrict__ wo, const float* __restrict__ wi,
    _Float16* __restrict__ A16) {
  int idx = blockIdx.x * 256 + threadIdx.x;        // [0, 2048*1024)
  int m = idx >> 10, k = idx & 1023;
  int h = m >> 2, g = m & 3;
  int j = k >> 9, c = k & 511;
  const float* w = (g == 0) ? wz : (g == 1) ? wf : (g == 2) ? wo : wi;
  A16[idx] = (_Float16)w[(h << 10) + (c << 1) + j];
}

// ---------------------------------------------------------------------------
// K1: transpose+convert x fp32 [B][C][T] -> XT16 [B][T][1024] fp16
//     k<512: x[b][k][t-1] (zeros at t=0), k>=512: x[b][k-512][t]
// ---------------------------------------------------------------------------
__global__ __launch_bounds__(256) void transpose_x(
    const float* __restrict__ x, _Float16* __restrict__ XT) {
  int bid = blockIdx.x;            // B * 8 * 64
  int b = bid >> 9;
  int rem = bid & 511;
  int c0 = (rem >> 6) * 64;
  int t0 = (rem & 63) * 64;
  __shared__ _Float16 tile[64][72];
  int tid = threadIdx.x;
#pragma unroll
  for (int it = 0; it < 4; ++it) {
    int idx = it * 256 + tid;      // 1024 tasks: 64 rows x 16 float4
    int ci = idx >> 4, tc = idx & 15;
    float4 v = *(const float4*)(x + (((size_t)b * C_DIM + c0 + ci) * T_DIM + t0 + tc * 4));
    tile[ci][tc * 4 + 0] = (_Float16)v.x;
    tile[ci][tc * 4 + 1] = (_Float16)v.y;
    tile[ci][tc * 4 + 2] = (_Float16)v.z;
    tile[ci][tc * 4 + 3] = (_Float16)v.w;
  }
  __syncthreads();
#pragma unroll
  for (int it = 0; it < 2; ++it) {
    int idx = it * 256 + tid;      // 512 tasks: 64 t-rows x 8 k-blocks
    int tr = idx >> 3, cb = idx & 7;
    half8 h;
#pragma unroll
    for (int e = 0; e < 8; ++e) h[e] = tile[cb * 8 + e][tr];
    int t = t0 + tr;
    size_t rowbase = ((size_t)b * T_DIM + t) * KTOT;
    *(half8*)(XT + rowbase + 512 + c0 + cb * 8) = h;                 // plane1: x[t]
    if (t + 1 < T_DIM)
      *(half8*)(XT + rowbase + KTOT + c0 + cb * 8) = h;              // plane0: x[t] -> row t+1
  }
  if (t0 == 0 && tid < 8) {        // zero-fill plane0 at t=0
    half8 z = {};
    *(half8*)(XT + ((size_t)b * T_DIM) * KTOT + c0 + tid * 8) = z;
  }
}

// ---------------------------------------------------------------------------
// K2: GEMM Y[2048, T] = A16[2048,1024] @ XT^T, fused activations.
//     128x128 tile, BK=64, 4 waves (2x2), mfma_f32_16x16x32_f16.
//     Outputs F,G,O fp16 [B][H][T].
// ---------------------------------------------------------------------------
__global__ __launch_bounds__(256, 2) void qrnn_gemm(
    const _Float16* __restrict__ A16, const _Float16* __restrict__ XT,
    const float* __restrict__ bz, const float* __restrict__ bf,
    const float* __restrict__ bo, const float* __restrict__ bi,
    _Float16* __restrict__ F, _Float16* __restrict__ G, _Float16* __restrict__ O) {
  __shared__ _Float16 lA[128 * 64];
  __shared__ _Float16 lB[128 * 64];
  int bid = blockIdx.x;                 // 8 * 16 * 32
  int b = bid >> 9;
  int rem = bid & 511;
  int m0 = (rem >> 5) * 128;
  int t0 = (rem & 31) * 128;
  int tid = threadIdx.x;
  int lane = tid & 63, wid = tid >> 6;
  int wm = (wid >> 1) * 64, wn = (wid & 1) * 64;

  f32x4 acc[4][4];
#pragma unroll
  for (int i = 0; i < 4; ++i)
#pragma unroll
    for (int j = 0; j < 4; ++j) acc[i][j] = (f32x4){0.f, 0.f, 0.f, 0.f};

  const _Float16* Ab = A16 + (size_t)m0 * KTOT;
  const _Float16* Bb = XT + ((size_t)b * T_DIM + t0) * KTOT;

  for (int kt = 0; kt < 16; ++kt) {
    int k0 = kt * 64;
    // stage A and B tiles: [128 rows][64 halves], XOR-swizzled 16B blocks.
    // LDS dest linear (idx*16); global source block = blk ^ (row&7).
#pragma unroll
    for (int it = 0; it < 4; ++it) {
      int idx = it * 256 + tid;
      int row = idx >> 3, blk = idx & 7;
      int gblk = blk ^ (row & 7);
      gload16(Ab + (size_t)row * KTOT + k0 + gblk * 8, (char*)lA + idx * 16);
    }
#pragma unroll
    for (int it = 0; it < 4; ++it) {
      int idx = it * 256 + tid;
      int row = idx >> 3, blk = idx & 7;
      int gblk = blk ^ (row & 7);
      gload16(Bb + (size_t)row * KTOT + k0 + gblk * 8, (char*)lB + idx * 16);
    }
    __syncthreads();
#pragma unroll
    for (int ks = 0; ks < 2; ++ks) {
      half8 av[4], bv[4];
#pragma unroll
      for (int i = 0; i < 4; ++i) {
        int row = wm + i * 16 + (lane & 15);
        int blk = (ks * 4 + (lane >> 4)) ^ (row & 7);
        av[i] = *(const half8*)(lA + row * 64 + blk * 8);
      }
#pragma unroll
      for (int j = 0; j < 4; ++j) {
        int row = wn + j * 16 + (lane & 15);
        int blk = (ks * 4 + (lane >> 4)) ^ (row & 7);
        bv[j] = *(const half8*)(lB + row * 64 + blk * 8);
      }
#pragma unroll
      for (int i = 0; i < 4; ++i)
#pragma unroll
        for (int j = 0; j < 4; ++j)
          acc[i][j] = __builtin_amdgcn_mfma_f32_16x16x32_f16(av[i], bv[j], acc[i][j], 0, 0, 0);
    }
    __syncthreads();
  }

  // epilogue: rows m = 4h+gate; lane group (lane>>4) holds gates r=0..3 of one h.
#pragma unroll
  for (int i = 0; i < 4; ++i) {
    int h = ((m0 + wm + i * 16) >> 2) + (lane >> 4);
    float vbz = bz[h], vbf = bf[h], vbo = bo[h], vbi = bi[h];
#pragma unroll
    for (int j = 0; j < 4; ++j) {
      int t = t0 + wn + j * 16 + (lane & 15);
      float yz = acc[i][j][0] + vbz;
      float yf = acc[i][j][1] + vbf;
      float yo = acc[i][j][2] + vbo;
      float yi = acc[i][j][3] + vbi;
      float zz = tanhf(yz);
      float ff = sigmoidf_(yf);
      float oo = sigmoidf_(yo);
      float ii = sigmoidf_(yi);
      size_t gi = ((size_t)b * H_DIM + h) * T_DIM + t;
      F[gi] = (_Float16)ff;
      G[gi] = (_Float16)(ii * zz);
      O[gi] = (_Float16)oo;
    }
  }
}

// ---------------------------------------------------------------------------
// K3: per-chunk composition (L=128, 32 chunks/seq): Fp = prod f, Gc = fold
// ---------------------------------------------------------------------------
__global__ __launch_bounds__(256) void scan_chunks(
    const _Float16* __restrict__ F, const _Float16* __restrict__ G,
    float* __restrict__ cF, float* __restrict__ cG) {
  int idx = blockIdx.x * 256 + threadIdx.x;   // [0, 4096*32)
  int ch = idx & 31;
  size_t bh = idx >> 5;
  const half8* f8 = (const half8*)(F + bh * T_DIM + ch * 128);
  const half8* g8 = (const half8*)(G + bh * T_DIM + ch * 128);
  float Fp = 1.f, Gc = 0.f;
#pragma unroll 4
  for (int t8 = 0; t8 < 16; ++t8) {
    half8 fv = f8[t8], gv = g8[t8];
#pragma unroll
    for (int e = 0; e < 8; ++e) {
      float fe = (float)fv[e];
      Gc = fe * Gc + (float)gv[e];
      Fp *= fe;
    }
  }
  cF[idx] = Fp;
  cG[idx] = Gc;
}

// ---------------------------------------------------------------------------
// K4: sequential scan over the 32 chunk-carries per (b,h); c_in per chunk.
// ---------------------------------------------------------------------------
__global__ __launch_bounds__(256) void scan_carry(
    const float* __restrict__ cF, const float* __restrict__ cG, float* __restrict__ cC) {
  int bh = blockIdx.x * 256 + threadIdx.x;    // [0, 4096)
  float c = 0.f;
#pragma unroll
  for (int j = 0; j < 32; ++j) {
    int id = bh * 32 + j;
    cC[id] = c;
    c = cF[id] * c + cG[id];
  }
}

// ---------------------------------------------------------------------------
// K5: apply scan within chunk, out = o * c  (fp32 [B][H][T])
// ---------------------------------------------------------------------------
__global__ __launch_bounds__(256) void scan_apply(
    const _Float16* __restrict__ F, const _Float16* __restrict__ G,
    const _Float16* __restrict__ O, const float* __restrict__ cC,
    float* __restrict__ out) {
  int idx = blockIdx.x * 256 + threadIdx.x;   // [0, 4096*32)
  int ch = idx & 31;
  size_t bh = idx >> 5;
  size_t base = bh * T_DIM + ch * 128;
  const half8* f8 = (const half8*)(F + base);
  const half8* g8 = (const half8*)(G + base);
  const half8* o8 = (const half8*)(O + base);
  float c = cC[idx];
  float4* out4 = (float4*)(out + base);
#pragma unroll 4
  for (int t8 = 0; t8 < 16; ++t8) {
    half8 fv = f8[t8], gv = g8[t8], ov = o8[t8];
    float r[8];
#pragma unroll
    for (int e = 0; e < 8; ++e) {
      c = (float)fv[e] * c + (float)gv[e];
      r[e] = (float)ov[e] * c;
    }
    out4[t8 * 2 + 0] = make_float4(r[0], r[1], r[2], r[3]);
    out4[t8 * 2 + 1] = make_float4(r[4], r[5], r[6], r[7]);
  }
}

// ---------------------------------------------------------------------------
extern "C" void kernel_launch(void* const* d_in, const int* in_sizes, int n_in,
                              void* d_out, int out_size, void* d_ws, size_t ws_size,
                              hipStream_t stream) {
  (void)in_sizes; (void)n_in; (void)out_size; (void)ws_size;
  const float* x  = (const float*)d_in[0];
  const float* wz = (const float*)d_in[1];
  const float* bz = (const float*)d_in[2];
  const float* wf = (const float*)d_in[3];
  const float* bf = (const float*)d_in[4];
  const float* wo = (const float*)d_in[5];
  const float* bo = (const float*)d_in[6];
  const float* wi = (const float*)d_in[7];
  const float* bi = (const float*)d_in[8];

  char* ws = (char*)d_ws;
  const size_t MB = 1ull << 20;
  _Float16* A16 = (_Float16*)(ws);                 //   4 MB
  _Float16* XT  = (_Float16*)(ws + 4 * MB);        //  64 MB
  _Float16* F   = (_Float16*)(ws + 68 * MB);       //  32 MB
  _Float16* G   = (_Float16*)(ws + 100 * MB);      //  32 MB
  _Float16* O   = (_Float16*)(ws + 132 * MB);      //  32 MB
  float* cF = (float*)(ws + 164 * MB);             // 512 KB
  float* cG = cF + 4096 * 32;
  float* cC = cG + 4096 * 32;

  pack_w<<<(MTOT * KTOT) / 256, 256, 0, stream>>>(wz, wf, wo, wi, A16);
  transpose_x<<<B_DIM * 8 * 64, 256, 0, stream>>>(x, XT);
  qrnn_gemm<<<B_DIM * 16 * 32, 256, 0, stream>>>(A16, XT, bz, bf, bo, bi, F, G, O);
  scan_chunks<<<(4096 * 32) / 256, 256, 0, stream>>>(F, G, cF, cG);
  scan_carry<<<4096 / 256, 256, 0, stream>>>(cF, cG, cC);
  scan_apply<<<(4096 * 32) / 256, 256, 0, stream>>>(F, G, O, cC, (float*)d_out);
}

// Round 2
// 320.277 us; speedup vs baseline: 1.1943x; 1.1943x over previous
//
#include <hip/hip_runtime.h>
#include <hip/hip_bf16.h>
#include <cstdint>

typedef _Float16 half8 __attribute__((ext_vector_type(8)));
typedef float f32x4 __attribute__((ext_vector_type(4)));

#define B_DIM 8
#define C_DIM 512
#define H_DIM 512
#define T_DIM 4096
#define KTOT 1024   // 2*C
#define MTOT 2048   // 4*H, interleaved m = 4*h + gate (z,f,o,i)

__device__ __forceinline__ void gload16(const void* g, void* l) {
  __builtin_amdgcn_global_load_lds(
      (const __attribute__((address_space(1))) unsigned int*)g,
      (__attribute__((address_space(3))) unsigned int*)l, 16, 0, 0);
}

__device__ __forceinline__ float sigmoidf_(float x) { return 1.0f / (1.0f + expf(-x)); }

// ---------------------------------------------------------------------------
// K0: pack weights fp32 [H][C][2] (4 gates) -> fp16 A16[m=4h+g][k=j*512+c]
// ---------------------------------------------------------------------------
__global__ __launch_bounds__(256) void pack_w(
    const float* __restrict__ wz, const float* __restrict__ wf,
    const float* __restrict__ wo, const float* __restrict__ wi,
    _Float16* __restrict__ A16) {
  int idx = blockIdx.x * 256 + threadIdx.x;        // [0, 2048*1024)
  int m = idx >> 10, k = idx & 1023;
  int h = m >> 2, g = m & 3;
  int j = k >> 9, c = k & 511;
  const float* w = (g == 0) ? wz : (g == 1) ? wf : (g == 2) ? wo : wi;
  A16[idx] = (_Float16)w[(h << 10) + (c << 1) + j];
}

// ---------------------------------------------------------------------------
// K1: transpose+convert x fp32 [B][C][T] -> XT16 [B][T][1024] fp16
//     k<512: x[b][k][t-1] (zeros at t=0), k>=512: x[b][k-512][t]
//     LDS tile stride 73 halves (odd) -> conflict-free transposed reads
// ---------------------------------------------------------------------------
__global__ __launch_bounds__(256) void transpose_x(
    const float* __restrict__ x, _Float16* __restrict__ XT) {
  int bid = blockIdx.x;            // B * 8 * 64
  int b = bid >> 9;
  int rem = bid & 511;
  int c0 = (rem >> 6) * 64;
  int t0 = (rem & 63) * 64;
  __shared__ _Float16 tile[64][73];
  int tid = threadIdx.x;
#pragma unroll
  for (int it = 0; it < 4; ++it) {
    int idx = it * 256 + tid;      // 1024 tasks: 64 rows x 16 float4
    int ci = idx >> 4, tc = idx & 15;
    float4 v = *(const float4*)(x + (((size_t)b * C_DIM + c0 + ci) * T_DIM + t0 + tc * 4));
    tile[ci][tc * 4 + 0] = (_Float16)v.x;
    tile[ci][tc * 4 + 1] = (_Float16)v.y;
    tile[ci][tc * 4 + 2] = (_Float16)v.z;
    tile[ci][tc * 4 + 3] = (_Float16)v.w;
  }
  __syncthreads();
#pragma unroll
  for (int it = 0; it < 2; ++it) {
    int idx = it * 256 + tid;      // 512 tasks: 64 t-rows x 8 k-blocks
    int tr = idx >> 3, cb = idx & 7;
    half8 h;
#pragma unroll
    for (int e = 0; e < 8; ++e) h[e] = tile[cb * 8 + e][tr];
    int t = t0 + tr;
    size_t rowbase = ((size_t)b * T_DIM + t) * KTOT;
    *(half8*)(XT + rowbase + 512 + c0 + cb * 8) = h;                 // plane1: x[t]
    if (t + 1 < T_DIM)
      *(half8*)(XT + rowbase + KTOT + c0 + cb * 8) = h;              // plane0: x[t] -> row t+1
  }
  if (t0 == 0 && tid < 8) {        // zero-fill plane0 at t=0
    half8 z = {};
    *(half8*)(XT + ((size_t)b * T_DIM) * KTOT + c0 + tid * 8) = z;
  }
}

// ---------------------------------------------------------------------------
// K2: GEMM Y[2048, T] = A16[2048,1024] @ XT^T, fused activations.
//     128x128 tile, BK=64, 4 waves (2x2), mfma_f32_16x16x32_f16.
//     Outputs F,G,O fp16 [B][H][T].
// ---------------------------------------------------------------------------
__global__ __launch_bounds__(256, 2) void qrnn_gemm(
    const _Float16* __restrict__ A16, const _Float16* __restrict__ XT,
    const float* __restrict__ bz, const float* __restrict__ bf,
    const float* __restrict__ bo, const float* __restrict__ bi,
    _Float16* __restrict__ F, _Float16* __restrict__ G, _Float16* __restrict__ O) {
  __shared__ _Float16 lA[128 * 64];
  __shared__ _Float16 lB[128 * 64];
  int bid = blockIdx.x;                 // 8 * 16 * 32
  int b = bid >> 9;
  int rem = bid & 511;
  int m0 = (rem >> 5) * 128;
  int t0 = (rem & 31) * 128;
  int tid = threadIdx.x;
  int lane = tid & 63, wid = tid >> 6;
  int wm = (wid >> 1) * 64, wn = (wid & 1) * 64;

  f32x4 acc[4][4];
#pragma unroll
  for (int i = 0; i < 4; ++i)
#pragma unroll
    for (int j = 0; j < 4; ++j) acc[i][j] = (f32x4){0.f, 0.f, 0.f, 0.f};

  const _Float16* Ab = A16 + (size_t)m0 * KTOT;
  const _Float16* Bb = XT + ((size_t)b * T_DIM + t0) * KTOT;

  for (int kt = 0; kt < 16; ++kt) {
    int k0 = kt * 64;
    // stage A and B tiles: [128 rows][64 halves], XOR-swizzled 16B blocks.
    // LDS dest linear (idx*16); global source block = blk ^ (row&7).
#pragma unroll
    for (int it = 0; it < 4; ++it) {
      int idx = it * 256 + tid;
      int row = idx >> 3, blk = idx & 7;
      int gblk = blk ^ (row & 7);
      gload16(Ab + (size_t)row * KTOT + k0 + gblk * 8, (char*)lA + idx * 16);
    }
#pragma unroll
    for (int it = 0; it < 4; ++it) {
      int idx = it * 256 + tid;
      int row = idx >> 3, blk = idx & 7;
      int gblk = blk ^ (row & 7);
      gload16(Bb + (size_t)row * KTOT + k0 + gblk * 8, (char*)lB + idx * 16);
    }
    __syncthreads();
#pragma unroll
    for (int ks = 0; ks < 2; ++ks) {
      half8 av[4], bv[4];
#pragma unroll
      for (int i = 0; i < 4; ++i) {
        int row = wm + i * 16 + (lane & 15);
        int blk = (ks * 4 + (lane >> 4)) ^ (row & 7);
        av[i] = *(const half8*)(lA + row * 64 + blk * 8);
      }
#pragma unroll
      for (int j = 0; j < 4; ++j) {
        int row = wn + j * 16 + (lane & 15);
        int blk = (ks * 4 + (lane >> 4)) ^ (row & 7);
        bv[j] = *(const half8*)(lB + row * 64 + blk * 8);
      }
#pragma unroll
      for (int i = 0; i < 4; ++i)
#pragma unroll
        for (int j = 0; j < 4; ++j)
          acc[i][j] = __builtin_amdgcn_mfma_f32_16x16x32_f16(av[i], bv[j], acc[i][j], 0, 0, 0);
    }
    __syncthreads();
  }

  // epilogue: rows m = 4h+gate; lane group (lane>>4) holds gates r=0..3 of one h.
#pragma unroll
  for (int i = 0; i < 4; ++i) {
    int h = ((m0 + wm + i * 16) >> 2) + (lane >> 4);
    float vbz = bz[h], vbf = bf[h], vbo = bo[h], vbi = bi[h];
#pragma unroll
    for (int j = 0; j < 4; ++j) {
      int t = t0 + wn + j * 16 + (lane & 15);
      float yz = acc[i][j][0] + vbz;
      float yf = acc[i][j][1] + vbf;
      float yo = acc[i][j][2] + vbo;
      float yi = acc[i][j][3] + vbi;
      float zz = tanhf(yz);
      float ff = sigmoidf_(yf);
      float oo = sigmoidf_(yo);
      float ii = sigmoidf_(yi);
      size_t gi = ((size_t)b * H_DIM + h) * T_DIM + t;
      F[gi] = (_Float16)ff;
      G[gi] = (_Float16)(ii * zz);
      O[gi] = (_Float16)oo;
    }
  }
}

// ---------------------------------------------------------------------------
// K3: fused scan. One block per (b,h) row (4096 blocks x 256 threads).
//     Stage F,G,O row (24KB) -> LDS via global_load_lds (swizzled source),
//     per-thread 16-elem chunk scanned in registers, block-scan of (F,G)
//     composites via shuffles, output staged through swizzled LDS (aliases
//     dead F/G region) -> coalesced float4 writes.
//     swz(bl) = bl ^ ((bl>>3)&7) on 16B blocks: involution, keeps each
//     aligned 128B window intact (coalescing preserved), spreads the
//     per-thread stride-2-block reads across all 8 bank-groups.
// ---------------------------------------------------------------------------
__global__ __launch_bounds__(256) void scan_fused(
    const _Float16* __restrict__ F, const _Float16* __restrict__ G,
    const _Float16* __restrict__ O, float* __restrict__ out) {
  __shared__ char smem[24 * 1024 + 64];
  _Float16* sF = (_Float16*)smem;              // 8KB: 512 16B-blocks
  _Float16* sG = (_Float16*)(smem + 8192);
  _Float16* sO = (_Float16*)(smem + 16384);
  float* sOut = (float*)smem;                  // 16KB, aliases sF+sG (dead after phase A)
  float* wFs = (float*)(smem + 24576);         // 4 + 4 floats
  float* wGs = wFs + 4;

  int tid = threadIdx.x;
  int lane = tid & 63, wv = tid >> 6;
  size_t base = (size_t)blockIdx.x * T_DIM;
  const _Float16* Fg = F + base;
  const _Float16* Gg = G + base;
  const _Float16* Og = O + base;

  // stage: LDS block idx holds global block swz(idx)
#pragma unroll
  for (int it = 0; it < 2; ++it) {
    int idx = it * 256 + tid;
    int sb = idx ^ ((idx >> 3) & 7);
    gload16(Fg + sb * 8, (char*)sF + idx * 16);
    gload16(Gg + sb * 8, (char*)sG + idx * 16);
    gload16(Og + sb * 8, (char*)sO + idx * 16);
  }
  asm volatile("s_waitcnt vmcnt(0)");
  __syncthreads();

  // phase A: per-thread chunk (16 elems = global blocks 2i, 2i+1) -> regs
  int i = tid;
  int b0 = (2 * i) ^ (((2 * i) >> 3) & 7);
  int b1 = (2 * i + 1) ^ (((2 * i + 1) >> 3) & 7);
  half8 f0 = *(half8*)((char*)sF + b0 * 16);
  half8 f1 = *(half8*)((char*)sF + b1 * 16);
  half8 g0 = *(half8*)((char*)sG + b0 * 16);
  half8 g1 = *(half8*)((char*)sG + b1 * 16);
  half8 o0 = *(half8*)((char*)sO + b0 * 16);
  half8 o1 = *(half8*)((char*)sO + b1 * 16);

  float Fp = 1.f, Gc = 0.f;
#pragma unroll
  for (int e = 0; e < 8; ++e) {
    float fe = (float)f0[e];
    Gc = fe * Gc + (float)g0[e];
    Fp *= fe;
  }
#pragma unroll
  for (int e = 0; e < 8; ++e) {
    float fe = (float)f1[e];
    Gc = fe * Gc + (float)g1[e];
    Fp *= fe;
  }

  // phase B: wave-inclusive scan of composites (compose: later∘earlier)
  float Fs = Fp, Gs = Gc;
#pragma unroll
  for (int d = 1; d < 64; d <<= 1) {
    float Fo = __shfl_up(Fs, d);
    float Go = __shfl_up(Gs, d);
    if (lane >= d) { Gs = Fs * Go + Gs; Fs = Fs * Fo; }
  }
  if (lane == 63) { wFs[wv] = Fs; wGs[wv] = Gs; }
  __syncthreads();   // publishes wave carries; also retires sF/sG reads before sOut reuse
  float carry = 0.f;
  for (int w = 0; w < wv; ++w) carry = wFs[w] * carry + wGs[w];
  float Fpr = __shfl_up(Fs, 1);
  float Gpr = __shfl_up(Gs, 1);
  float cin = (lane == 0) ? carry : Fpr * carry + Gpr;

  // phase C: rescan with carry-in, stage o*c into swizzled sOut
  float c = cin;
  float4 r0, r1, r2, r3;
#define QSTEP(fv, gv, ov, e, dst) \
  { c = (float)fv[e] * c + (float)gv[e]; dst = (float)ov[e] * c; }
  QSTEP(f0, g0, o0, 0, r0.x) QSTEP(f0, g0, o0, 1, r0.y)
  QSTEP(f0, g0, o0, 2, r0.z) QSTEP(f0, g0, o0, 3, r0.w)
  QSTEP(f0, g0, o0, 4, r1.x) QSTEP(f0, g0, o0, 5, r1.y)
  QSTEP(f0, g0, o0, 6, r1.z) QSTEP(f0, g0, o0, 7, r1.w)
  QSTEP(f1, g1, o1, 0, r2.x) QSTEP(f1, g1, o1, 1, r2.y)
  QSTEP(f1, g1, o1, 2, r2.z) QSTEP(f1, g1, o1, 3, r2.w)
  QSTEP(f1, g1, o1, 4, r3.x) QSTEP(f1, g1, o1, 5, r3.y)
  QSTEP(f1, g1, o1, 6, r3.z) QSTEP(f1, g1, o1, 7, r3.w)
#undef QSTEP
  {
    int obl = 4 * i;
    int s0 = (obl + 0) ^ (((obl + 0) >> 3) & 7);
    int s1 = (obl + 1) ^ (((obl + 1) >> 3) & 7);
    int s2 = (obl + 2) ^ (((obl + 2) >> 3) & 7);
    int s3 = (obl + 3) ^ (((obl + 3) >> 3) & 7);
    *(float4*)((char*)sOut + s0 * 16) = r0;
    *(float4*)((char*)sOut + s1 * 16) = r1;
    *(float4*)((char*)sOut + s2 * 16) = r2;
    *(float4*)((char*)sOut + s3 * 16) = r3;
  }
  __syncthreads();

  // coalesced writeback: linear global block idx <- sOut block swz(idx)
  float* og = out + base;
#pragma unroll
  for (int it = 0; it < 4; ++it) {
    int idx = it * 256 + tid;
    int sb = idx ^ ((idx >> 3) & 7);
    *(float4*)(og + idx * 4) = *(float4*)((char*)sOut + sb * 16);
  }
}

// ---------------------------------------------------------------------------
extern "C" void kernel_launch(void* const* d_in, const int* in_sizes, int n_in,
                              void* d_out, int out_size, void* d_ws, size_t ws_size,
                              hipStream_t stream) {
  (void)in_sizes; (void)n_in; (void)out_size; (void)ws_size;
  const float* x  = (const float*)d_in[0];
  const float* wz = (const float*)d_in[1];
  const float* bz = (const float*)d_in[2];
  const float* wf = (const float*)d_in[3];
  const float* bf = (const float*)d_in[4];
  const float* wo = (const float*)d_in[5];
  const float* bo = (const float*)d_in[6];
  const float* wi = (const float*)d_in[7];
  const float* bi = (const float*)d_in[8];

  char* ws = (char*)d_ws;
  const size_t MB = 1ull << 20;
  _Float16* A16 = (_Float16*)(ws);                 //   4 MB
  _Float16* XT  = (_Float16*)(ws + 4 * MB);        //  64 MB
  _Float16* F   = (_Float16*)(ws + 68 * MB);       //  32 MB
  _Float16* G   = (_Float16*)(ws + 100 * MB);      //  32 MB
  _Float16* O   = (_Float16*)(ws + 132 * MB);      //  32 MB

  pack_w<<<(MTOT * KTOT) / 256, 256, 0, stream>>>(wz, wf, wo, wi, A16);
  transpose_x<<<B_DIM * 8 * 64, 256, 0, stream>>>(x, XT);
  qrnn_gemm<<<B_DIM * 16 * 32, 256, 0, stream>>>(A16, XT, bz, bf, bo, bi, F, G, O);
  scan_fused<<<B_DIM * H_DIM, 256, 0, stream>>>(F, G, O, (float*)d_out);
}